// Round 1
// baseline (119.912 us; speedup 1.0000x reference)
//
#include <hip/hip_runtime.h>

// YOLO loss: pred (B,30,7,7) f32, label (B,30,7,7) f32 -> scalar f32 (sum/B).
// Memory-bound: 96 MB read once. One thread per (b,i,j) cell.

__device__ __forceinline__ float sq(float x) { return x * x; }

__global__ __launch_bounds__(256) void yolo_loss_kernel(
    const float* __restrict__ pred, const float* __restrict__ label,
    float* __restrict__ out, int ncells, float inv_B)
{
    const float Gc = 1.0f / 7.0f;
    int g = blockIdx.x * blockDim.x + threadIdx.x;
    float cell = 0.0f;
    if (g < ncells) {
        int b = g / 49;
        int s = g - b * 49;
        int i = s / 7;          // axis 2, paired with x
        int j = s - i * 7;      // axis 3, paired with y
        const float* __restrict__ P = pred  + (size_t)b * 1470 + s;
        const float* __restrict__ L = label + (size_t)b * 1470 + s;

        float p[30], l[30];
#pragma unroll
        for (int c = 0; c < 30; ++c) {
            p[c] = P[c * 49];
            l[c] = L[c * 49];
        }

        float fi = (float)i, fj = (float)j;

        // box 1 (pred ch 0..3)
        float cx1 = (p[0] + fi) * Gc, cy1 = (p[1] + fj) * Gc;
        float a_x1 = cx1 - p[2] * 0.5f, a_y1 = cy1 - p[3] * 0.5f;
        float a_x2 = cx1 + p[2] * 0.5f, a_y2 = cy1 + p[3] * 0.5f;
        // box 2 (pred ch 5..8)
        float cx2 = (p[5] + fi) * Gc, cy2 = (p[6] + fj) * Gc;
        float b_x1 = cx2 - p[7] * 0.5f, b_y1 = cy2 - p[8] * 0.5f;
        float b_x2 = cx2 + p[7] * 0.5f, b_y2 = cy2 + p[8] * 0.5f;
        // degenerate label point-box
        float lx = (l[0] + fi) * Gc - l[2] * 0.5f;
        float ly = (l[1] + fj) * Gc - l[3] * 0.5f;

        // iou(box, point-box) — faithful to reference (area_b = 0)
        auto iou_pt = [&](float x1, float y1, float x2, float y2) {
            float ix = fminf(x2, lx) - fmaxf(x1, lx);
            float iy = fminf(y2, ly) - fmaxf(y1, ly);
            float inter = fmaxf(ix, 0.0f) * fmaxf(iy, 0.0f);
            float area_a = (x2 - x1) * (y2 - y1);
            float uni = area_a + 0.0f - inter;
            float denom = (uni == 0.0f) ? 1.0f : uni;
            return inter / denom;
        };

        float iou1 = iou_pt(a_x1, a_y1, a_x2, a_y2);
        float iou2 = iou_pt(b_x1, b_y1, b_x2, b_y2);
        bool sel1 = iou1 > iou2;

        float t1 = sq(p[0] - l[0]) + sq(p[1] - l[1])
                 + sq(sqrtf(p[2]) - sqrtf(l[2])) + sq(sqrtf(p[3]) - sqrtf(l[3]));
        float t2 = sq(p[5] - l[5]) + sq(p[6] - l[6])
                 + sq(sqrtf(p[7]) - sqrtf(l[7])) + sq(sqrtf(p[8]) - sqrtf(l[8]));

        float obj_term     = sel1 ? t1 : t2;
        float conf_term    = sel1 ? sq(p[4] - 1.0f) : sq(p[9] - 1.0f);
        float noobj_obj    = sel1 ? sq(p[9]) : sq(p[4]);
        float noobj_empty  = sq(p[4]) + sq(p[9]);

        float cls = 0.0f;
#pragma unroll
        for (int c = 10; c < 30; ++c) cls += sq(p[c] - l[c]);

        bool obj = (l[4] == 1.0f);
        // obj_weight = 0.5, noobj_weight = 0.5
        cell = obj ? (0.5f * obj_term + conf_term + cls + 0.5f * noobj_obj)
                   : (0.5f * noobj_empty);
    }

    // wave (64-lane) shuffle reduce
#pragma unroll
    for (int off = 32; off > 0; off >>= 1)
        cell += __shfl_down(cell, off, 64);

    __shared__ float smem[4];
    int lane = threadIdx.x & 63;
    int wid  = threadIdx.x >> 6;
    if (lane == 0) smem[wid] = cell;
    __syncthreads();
    if (threadIdx.x == 0) {
        float bs = smem[0] + smem[1] + smem[2] + smem[3];
        atomicAdd(out, bs * inv_B);
    }
}

extern "C" void kernel_launch(void* const* d_in, const int* in_sizes, int n_in,
                              void* d_out, int out_size, void* d_ws, size_t ws_size,
                              hipStream_t stream) {
    const float* pred  = (const float*)d_in[0];
    const float* label = (const float*)d_in[1];
    float* out = (float*)d_out;

    int B = in_sizes[0] / (30 * 49);
    int ncells = B * 49;

    hipMemsetAsync(d_out, 0, sizeof(float), stream);

    int block = 256;
    int grid = (ncells + block - 1) / block;
    yolo_loss_kernel<<<grid, block, 0, stream>>>(pred, label, out, ncells,
                                                 1.0f / (float)B);
}